// Round 9
// baseline (318.322 us; speedup 1.0000x reference)
//
#include <hip/hip_runtime.h>
#include <cstdint>
#include <cstddef>

#define NFEATS 128
#define NHIDS  128
#define NOUT   64
#define SB     256    // nodes per bucket (dst >> 8)
#define CHUNK  4096   // edges per chunk in the radix partition

using bf16x8 = __attribute__((ext_vector_type(8))) short;
using f32x4  = __attribute__((ext_vector_type(4))) float;

__device__ inline unsigned short f2bf(float f) {           // round-to-nearest-even
    union { float f; unsigned int u; } v; v.f = f;
    unsigned int r = (v.u + 0x7FFFu + ((v.u >> 16) & 1u)) >> 16;
    return (unsigned short)r;
}
__device__ inline float bflo(unsigned int u) { return __uint_as_float(u << 16); }
__device__ inline float bfhi(unsigned int u) { return __uint_as_float(u & 0xFFFF0000u); }

// ---------------------------------------------------------------------------
// Edge-index dtype detection (int64 vs int32). flag=1 -> int32.
// ---------------------------------------------------------------------------
__global__ void detect_kernel(const void* p, int* flag, long long n_nodes) {
    const long long* q = (const long long*)p;
    long long v = q[threadIdx.x];
    int bad = (v < 0 || v >= n_nodes) ? 1 : 0;
    unsigned long long m = __ballot(bad);
    if (threadIdx.x == 0) *flag = (m != 0ULL) ? 1 : 0;
}

// ---------------------------------------------------------------------------
// Phase 1a: per-(chunk,bucket) histogram. histT[b*nch + c].
// LDS cursors only — NO global atomics (R5 lesson: same-address returning
// atomics serialize at ~234 ns; fan-in must stay tiny).
// ---------------------------------------------------------------------------
__global__ void hist_kernel(const void* __restrict__ edges, const int* __restrict__ flag,
                            int* __restrict__ histT, int ne, int nch, int nbkt) {
    __shared__ int h[1024];
    int c = blockIdx.x, t = threadIdx.x;              // blockDim = 512
    for (int i = t; i < nbkt; i += 512) h[i] = 0;
    __syncthreads();
    int beg = c * CHUNK, end = min(ne, beg + CHUNK);
    bool is32 = (*flag != 0);
    for (int i = beg + t; i < end; i += 512) {
        int d = is32 ? ((const int*)edges)[ne + i]
                     : (int)((const long long*)edges)[ne + i];
        atomicAdd(&h[d >> 8], 1);
    }
    __syncthreads();
    for (int i = t; i < nbkt; i += 512)
        histT[i * nch + c] = h[i];
}

// ---------------------------------------------------------------------------
// Exclusive scan over histT (m = nbkt*nch elements) -> chunk_base
// ---------------------------------------------------------------------------
__global__ void scan_block(const int* __restrict__ v, int* __restrict__ incl,
                           int* __restrict__ partial, int n) {
    __shared__ int sh[256];
    int t = threadIdx.x;
    int i = blockIdx.x * 256 + t;
    sh[t] = (i < n) ? v[i] : 0;
    __syncthreads();
    for (int off = 1; off < 256; off <<= 1) {
        int add = (t >= off) ? sh[t - off] : 0;
        __syncthreads();
        sh[t] += add;
        __syncthreads();
    }
    if (i < n) incl[i] = sh[t];
    if (t == 255) partial[blockIdx.x] = sh[255];
}

__global__ void scan_partials(int* partial, int nb) {
    __shared__ int sh[512];
    __shared__ int carry;
    int t = threadIdx.x;
    if (t == 0) carry = 0;
    __syncthreads();
    for (int base = 0; base < nb; base += 512) {
        int idx = base + t;
        sh[t] = (idx < nb) ? partial[idx] : 0;
        __syncthreads();
        for (int off = 1; off < 512; off <<= 1) {
            int add = (t >= off) ? sh[t - off] : 0;
            __syncthreads();
            sh[t] += add;
            __syncthreads();
        }
        int excl = carry + ((t == 0) ? 0 : sh[t - 1]);
        if (idx < nb) partial[idx] = excl;
        __syncthreads();
        if (t == 0) carry += sh[511];
        __syncthreads();
    }
}

__global__ void finalize_scan(const int* __restrict__ incl, const int* __restrict__ v,
                              const int* __restrict__ partial,
                              int* __restrict__ excl, int m) {
    int i = blockIdx.x * blockDim.x + threadIdx.x;
    if (i < m) excl[i] = partial[i >> 8] + incl[i] - v[i];
}

// ---------------------------------------------------------------------------
// Phase 1b: re-read chunk, LDS-cursor placement into precomputed per-
// (chunk,bucket) contiguous ranges. rec = (src << 8) | (dst & 255).
// ---------------------------------------------------------------------------
__global__ void scatter_chunks(const void* __restrict__ edges, const int* __restrict__ flag,
                               const int* __restrict__ chunk_base,
                               unsigned int* __restrict__ ebuf,
                               int ne, int nch, int nbkt) {
    __shared__ int cur[1024];
    int c = blockIdx.x, t = threadIdx.x;              // blockDim = 512
    for (int i = t; i < nbkt; i += 512) cur[i] = chunk_base[i * nch + c];
    __syncthreads();
    int beg = c * CHUNK, end = min(ne, beg + CHUNK);
    bool is32 = (*flag != 0);
    for (int i = beg + t; i < end; i += 512) {
        int s, d;
        if (is32) {
            s = ((const int*)edges)[i];
            d = ((const int*)edges)[ne + i];
        } else {
            s = (int)((const long long*)edges)[i];
            d = (int)((const long long*)edges)[ne + i];
        }
        int pos = atomicAdd(&cur[d >> 8], 1);
        ebuf[pos] = ((unsigned int)s << 8) | (unsigned int)(d & (SB - 1));
    }
}

// ---------------------------------------------------------------------------
// Phase 2: one block per bucket. LDS degree histogram + LDS scan ->
// row_ptr, dinv, CU-local scatter of csr_src, and a bucket-local
// DEGREE-SORTED node permutation (R8 post-mortem: aggregate waves run
// max(deg) over their lane-groups -> 43-55% padded gather slots; sorting
// equalizes trip counts within a wave).
// ---------------------------------------------------------------------------
__global__ void bucket_finalize(const unsigned int* __restrict__ ebuf,
                                const int* __restrict__ chunk_base,
                                int* __restrict__ row_ptr, float* __restrict__ dinv,
                                int* __restrict__ csr_src, int* __restrict__ perm,
                                int n, int e, int nch, int nbkt) {
    __shared__ int deg[SB];
    __shared__ int scn[SB];    // scan scratch (row_ptr scan, then deg-hist scan)
    __shared__ int cur[SB];
    __shared__ int dh[SB];     // degree histogram (key clamped to SB-1)
    __shared__ int cnt[SB];    // placement counters
    int b = blockIdx.x, t = threadIdx.x;              // blockDim = SB = 256
    int node0 = b * SB;
    int nn = min(SB, n - node0);
    int base = chunk_base[b * nch];
    int bend = (b == nbkt - 1) ? e : chunk_base[(b + 1) * nch];

    deg[t] = 0; dh[t] = 0; cnt[t] = 0;
    __syncthreads();
    for (int i = base + t; i < bend; i += SB)
        atomicAdd(&deg[ebuf[i] & (SB - 1)], 1);
    __syncthreads();

    // scan degrees -> local row offsets
    scn[t] = deg[t];
    __syncthreads();
    for (int off = 1; off < SB; off <<= 1) {
        int add = (t >= off) ? scn[t - off] : 0;
        __syncthreads();
        scn[t] += add;
        __syncthreads();
    }
    int lrow = base + scn[t] - deg[t];
    cur[t] = lrow;
    if (t < nn) {
        row_ptr[node0 + t] = lrow;
        dinv[node0 + t]    = rsqrtf((float)(deg[t] + 1));
    }
    if (b == nbkt - 1 && t == 0) row_ptr[n] = e;

    // bucket-local counting sort by degree -> perm
    int key = min(deg[t], SB - 1);
    if (t < nn) atomicAdd(&dh[key], 1);
    __syncthreads();
    scn[t] = dh[t];
    __syncthreads();
    for (int off = 1; off < SB; off <<= 1) {
        int add = (t >= off) ? scn[t - off] : 0;
        __syncthreads();
        scn[t] += add;
        __syncthreads();
    }
    if (t < nn) {
        int pos = (scn[key] - dh[key]) + atomicAdd(&cnt[key], 1);
        perm[node0 + pos] = node0 + t;
    }
    __syncthreads();

    // CU-local csr scatter
    for (int i = base + t; i < bend; i += SB) {
        unsigned int r = ebuf[i];
        int pos = atomicAdd(&cur[r & (SB - 1)], 1);
        csr_src[pos] = (int)(r >> 8);
    }
}

// ---------------------------------------------------------------------------
// W [K][NC] fp32 row-major  ->  Wt [NC][K] bf16 (transposed)
// ---------------------------------------------------------------------------
__global__ void wt_bf16(const float* __restrict__ W, unsigned short* __restrict__ Wt,
                        int K, int NC) {
    int i = blockIdx.x * blockDim.x + threadIdx.x;
    if (i < K * NC) {
        int k = i / NC, n = i % NC;
        Wt[n * K + k] = f2bf(W[i]);
    }
}

// ---------------------------------------------------------------------------
// MFMA GEMM: hs[r][c] = bf16( dinv[r] * sum_k X[r][k] * W[k][c] )
// Layouts (verified, learn_hip m89/m91/m120); KP=136 -> 2-way LDS aliasing
// (free, m136).
// ---------------------------------------------------------------------------
template <int NC, bool F32IN>
__launch_bounds__(256)
__global__ void gemm_mfma(const void* __restrict__ Xin,
                          const unsigned short* __restrict__ Wt,
                          const float* __restrict__ dinv,
                          unsigned short* __restrict__ hs, int nrows) {
    constexpr int K  = 128;
    constexpr int KP = 136;
    __shared__ __align__(16) unsigned short Xl[64 * KP];
    __shared__ __align__(16) unsigned short Wl[NC * KP];

    const int tid  = threadIdx.x;
    const int row0 = blockIdx.x * 64;

    for (int i = tid; i < 64 * (K / 4); i += 256) {
        int r  = i >> 5;
        int c4 = i & 31;
        int gr = row0 + r;
        ushort4 v = make_ushort4(0, 0, 0, 0);
        if (gr < nrows) {
            if (F32IN) {
                float4 f = ((const float4*)((const float*)Xin + (size_t)gr * K))[c4];
                v.x = f2bf(f.x); v.y = f2bf(f.y); v.z = f2bf(f.z); v.w = f2bf(f.w);
            } else {
                v = ((const ushort4*)((const unsigned short*)Xin + (size_t)gr * K))[c4];
            }
        }
        *(ushort4*)(Xl + r * KP + c4 * 4) = v;
    }
    for (int i = tid; i < NC * (K / 4); i += 256) {
        int r  = i >> 5;
        int c4 = i & 31;
        ushort4 v = ((const ushort4*)(Wt + (size_t)r * K))[c4];
        *(ushort4*)(Wl + r * KP + c4 * 4) = v;
    }
    __syncthreads();

    const int wv   = tid >> 6;
    const int lane = tid & 63;
    const int m    = lane & 15;
    const int q    = lane >> 4;

    bf16x8 af[4];
#pragma unroll
    for (int kt = 0; kt < 4; ++kt)
        af[kt] = *(const bf16x8*)(Xl + (wv * 16 + m) * KP + kt * 32 + q * 8);

    const int rbase = row0 + wv * 16 + q * 4;
    float dv[4];
#pragma unroll
    for (int i = 0; i < 4; ++i)
        dv[i] = (rbase + i < nrows) ? dinv[rbase + i] : 0.f;

#pragma unroll
    for (int nt = 0; nt < NC / 16; ++nt) {
        f32x4 acc = {0.f, 0.f, 0.f, 0.f};
#pragma unroll
        for (int kt = 0; kt < 4; ++kt) {
            bf16x8 bfr = *(const bf16x8*)(Wl + (nt * 16 + m) * KP + kt * 32 + q * 8);
            acc = __builtin_amdgcn_mfma_f32_16x16x32_bf16(af[kt], bfr, acc, 0, 0, 0);
        }
#pragma unroll
        for (int i = 0; i < 4; ++i) {
            int g = rbase + i;
            if (g < nrows)
                hs[(size_t)g * NC + nt * 16 + m] = f2bf(acc[i] * dv[i]);
        }
    }
}

// ---------------------------------------------------------------------------
// CSR gather-reduce + epilogue, bf16 features (fp32 accumulate).
// Nodes processed in degree-sorted order via perm[] so lane-groups within a
// wave have near-equal trip counts. TPN = F/8 lanes per node, uint4 per
// lane, batches of 8 edges in flight.
// ---------------------------------------------------------------------------
template <int F, bool RELU, bool OUTBF>
__launch_bounds__(256)
__global__ void aggregate_bf16(const int* __restrict__ perm,
                               const int* __restrict__ row_ptr,
                               const int* __restrict__ csr_src,
                               const uint4* __restrict__ hsu,
                               const float* __restrict__ dinv,
                               const float* __restrict__ b,
                               void* __restrict__ out, int n) {
    constexpr int TPN = F / 8;          // lanes per node (16 / 8)
    constexpr int NPB = 256 / TPN;      // nodes per block (16 / 32)
    int idx = blockIdx.x * NPB + threadIdx.x / TPN;
    int t   = threadIdx.x % TPN;
    if (idx >= n) return;
    int node = perm[idx];

    uint4 u = hsu[(size_t)node * TPN + t];           // self-loop term
    float a[8];
    a[0] = bflo(u.x); a[1] = bfhi(u.x); a[2] = bflo(u.y); a[3] = bfhi(u.y);
    a[4] = bflo(u.z); a[5] = bfhi(u.z); a[6] = bflo(u.w); a[7] = bfhi(u.w);

    int beg = row_ptr[node], end = row_ptr[node + 1];
    for (int e = beg; e < end; e += 8) {
        int rem = end - e;                            // >= 1
        int s[8];
#pragma unroll
        for (int j = 0; j < 8; ++j)
            s[j] = csr_src[e + (j < rem ? j : 0)];
        uint4 v[8];
#pragma unroll
        for (int j = 0; j < 8; ++j)
            v[j] = hsu[(size_t)s[j] * TPN + t];
#pragma unroll
        for (int j = 0; j < 8; ++j) {
            if (j < rem) {
                a[0] += bflo(v[j].x); a[1] += bfhi(v[j].x);
                a[2] += bflo(v[j].y); a[3] += bfhi(v[j].y);
                a[4] += bflo(v[j].z); a[5] += bfhi(v[j].z);
                a[6] += bflo(v[j].w); a[7] += bfhi(v[j].w);
            }
        }
    }

    float dvn = dinv[node];
    float4 b0 = ((const float4*)b)[2 * t];
    float4 b1 = ((const float4*)b)[2 * t + 1];
    float o[8];
    o[0] = a[0] * dvn + b0.x; o[1] = a[1] * dvn + b0.y;
    o[2] = a[2] * dvn + b0.z; o[3] = a[3] * dvn + b0.w;
    o[4] = a[4] * dvn + b1.x; o[5] = a[5] * dvn + b1.y;
    o[6] = a[6] * dvn + b1.z; o[7] = a[7] * dvn + b1.w;
    if (RELU) {
#pragma unroll
        for (int j = 0; j < 8; ++j) o[j] = fmaxf(o[j], 0.f);
    }
    if (OUTBF) {
        uint4 ov;
        ov.x = (unsigned int)f2bf(o[0]) | ((unsigned int)f2bf(o[1]) << 16);
        ov.y = (unsigned int)f2bf(o[2]) | ((unsigned int)f2bf(o[3]) << 16);
        ov.z = (unsigned int)f2bf(o[4]) | ((unsigned int)f2bf(o[5]) << 16);
        ov.w = (unsigned int)f2bf(o[6]) | ((unsigned int)f2bf(o[7]) << 16);
        ((uint4*)out)[(size_t)node * TPN + t] = ov;
    } else {
        float4* op = (float4*)out + (size_t)node * (F / 4) + 2 * t;
        op[0] = make_float4(o[0], o[1], o[2], o[3]);
        op[1] = make_float4(o[4], o[5], o[6], o[7]);
    }
}

// ---------------------------------------------------------------------------
extern "C" void kernel_launch(void* const* d_in, const int* in_sizes, int n_in,
                              void* d_out, int out_size, void* d_ws, size_t ws_size,
                              hipStream_t stream) {
    const void*  edge = d_in[0];
    const float* x    = (const float*)d_in[1];
    const float* W1   = (const float*)d_in[2];
    const float* b1   = (const float*)d_in[3];
    const float* W2   = (const float*)d_in[4];
    const float* b2   = (const float*)d_in[5];
    float* out = (float*)d_out;

    const int E    = in_sizes[0] / 2;
    const int N    = in_sizes[1] / NFEATS;
    const int NBKT = (N + SB - 1) / SB;        // 391
    const int NCH  = (E + CHUNK - 1) / CHUNK;  // 391
    const int M    = NBKT * NCH;               // histogram matrix size

    char* w = (char*)d_ws;
    auto carve = [&](size_t bytes) { void* p = w; w += (bytes + 255) & ~(size_t)255; return p; };
    int*            flag       = (int*)           carve(256);
    int*            histT      = (int*)           carve(sizeof(int) * (size_t)M);
    int*            incl       = (int*)           carve(sizeof(int) * (size_t)M);
    int*            partial    = (int*)           carve(sizeof(int) * 4096);
    int*            chunk_base = (int*)           carve(sizeof(int) * (size_t)M);
    int*            row_ptr    = (int*)           carve(sizeof(int) * ((size_t)N + 1));
    int*            perm       = (int*)           carve(sizeof(int) * (size_t)N);
    float*          dinv       = (float*)         carve(sizeof(float) * (size_t)N);
    unsigned int*   ebuf       = (unsigned int*)  carve(sizeof(int) * (size_t)E);
    int*            csr_src    = (int*)           carve(sizeof(int) * (size_t)E);
    unsigned short* Wt1        = (unsigned short*)carve(2 * (size_t)NFEATS * NHIDS);
    unsigned short* Wt2        = (unsigned short*)carve(2 * (size_t)NHIDS * NOUT);
    unsigned short* hs1        = (unsigned short*)carve(2 * (size_t)N * NHIDS);
    unsigned short* h1         = (unsigned short*)carve(2 * (size_t)N * NHIDS);
    unsigned short* hs2        = (unsigned short*)carve(2 * (size_t)N * NOUT);

    const int B   = 256;
    const int nbS = (M + 255) / 256;           // scan blocks over histogram

    detect_kernel<<<1, 64, 0, stream>>>(edge, flag, (long long)N);

    // CSR build: chunk histograms -> scan -> LDS-cursor partition -> finalize
    hist_kernel<<<NCH, 512, 0, stream>>>(edge, flag, histT, E, NCH, NBKT);
    scan_block<<<nbS, 256, 0, stream>>>(histT, incl, partial, M);
    scan_partials<<<1, 512, 0, stream>>>(partial, nbS);
    finalize_scan<<<nbS, 256, 0, stream>>>(incl, histT, partial, chunk_base, M);
    scatter_chunks<<<NCH, 512, 0, stream>>>(edge, flag, chunk_base, ebuf, E, NCH, NBKT);
    bucket_finalize<<<NBKT, SB, 0, stream>>>(ebuf, chunk_base, row_ptr, dinv, csr_src,
                                             perm, N, E, NCH, NBKT);

    wt_bf16<<<(NFEATS * NHIDS + B - 1) / B, B, 0, stream>>>(W1, Wt1, NFEATS, NHIDS);
    wt_bf16<<<(NHIDS * NOUT + B - 1) / B, B, 0, stream>>>(W2, Wt2, NHIDS, NOUT);

    // ---- layer 1 ----
    gemm_mfma<NHIDS, true><<<(N + 63) / 64, B, 0, stream>>>(x, Wt1, dinv, hs1, N);
    {
        constexpr int NPB = 256 / (NHIDS / 8);   // 16 nodes per block
        aggregate_bf16<NHIDS, true, true><<<(N + NPB - 1) / NPB, B, 0, stream>>>(
            perm, row_ptr, csr_src, (const uint4*)hs1, dinv, b1, h1, N);
    }

    // ---- layer 2 ----
    gemm_mfma<NOUT, false><<<(N + 63) / 64, B, 0, stream>>>(h1, Wt2, dinv, hs2, N);
    {
        constexpr int NPB = 256 / (NOUT / 8);    // 32 nodes per block
        aggregate_bf16<NOUT, false, false><<<(N + NPB - 1) / NPB, B, 0, stream>>>(
            perm, row_ptr, csr_src, (const uint4*)hs2, dinv, b2, out, N);
    }
}

// Round 10
// 277.037 us; speedup vs baseline: 1.1490x; 1.1490x over previous
//
#include <hip/hip_runtime.h>
#include <cstdint>
#include <cstddef>

#define NFEATS 128
#define NHIDS  128
#define NOUT   64
#define SB     256    // nodes per bucket (dst >> 8)
#define CHUNK  4096   // edges per chunk in the radix partition

using bf16x8 = __attribute__((ext_vector_type(8))) short;
using f32x4  = __attribute__((ext_vector_type(4))) float;

__device__ inline unsigned short f2bf(float f) {           // round-to-nearest-even
    union { float f; unsigned int u; } v; v.f = f;
    unsigned int r = (v.u + 0x7FFFu + ((v.u >> 16) & 1u)) >> 16;
    return (unsigned short)r;
}
__device__ inline float bflo(unsigned int u) { return __uint_as_float(u << 16); }
__device__ inline float bfhi(unsigned int u) { return __uint_as_float(u & 0xFFFF0000u); }

// ---------------------------------------------------------------------------
// Edge-index dtype detection (int64 vs int32). flag=1 -> int32.
// ---------------------------------------------------------------------------
__global__ void detect_kernel(const void* p, int* flag, long long n_nodes) {
    const long long* q = (const long long*)p;
    long long v = q[threadIdx.x];
    int bad = (v < 0 || v >= n_nodes) ? 1 : 0;
    unsigned long long m = __ballot(bad);
    if (threadIdx.x == 0) *flag = (m != 0ULL) ? 1 : 0;
}

// ---------------------------------------------------------------------------
// Phase 1a: per-(chunk,bucket) histogram. histT[b*nch + c].
// LDS cursors only — NO global cursor atomics (R5: same-address returning
// atomics serialize at ~234 ns).
// ---------------------------------------------------------------------------
__global__ void hist_kernel(const void* __restrict__ edges, const int* __restrict__ flag,
                            int* __restrict__ histT, int ne, int nch, int nbkt) {
    __shared__ int h[1024];
    int c = blockIdx.x, t = threadIdx.x;              // blockDim = 512
    for (int i = t; i < nbkt; i += 512) h[i] = 0;
    __syncthreads();
    int beg = c * CHUNK, end = min(ne, beg + CHUNK);
    bool is32 = (*flag != 0);
    for (int i = beg + t; i < end; i += 512) {
        int d = is32 ? ((const int*)edges)[ne + i]
                     : (int)((const long long*)edges)[ne + i];
        atomicAdd(&h[d >> 8], 1);
    }
    __syncthreads();
    for (int i = t; i < nbkt; i += 512)
        histT[i * nch + c] = h[i];
}

// ---------------------------------------------------------------------------
// Exclusive scan over histT (m = nbkt*nch elements) -> chunk_base
// ---------------------------------------------------------------------------
__global__ void scan_block(const int* __restrict__ v, int* __restrict__ incl,
                           int* __restrict__ partial, int n) {
    __shared__ int sh[256];
    int t = threadIdx.x;
    int i = blockIdx.x * 256 + t;
    sh[t] = (i < n) ? v[i] : 0;
    __syncthreads();
    for (int off = 1; off < 256; off <<= 1) {
        int add = (t >= off) ? sh[t - off] : 0;
        __syncthreads();
        sh[t] += add;
        __syncthreads();
    }
    if (i < n) incl[i] = sh[t];
    if (t == 255) partial[blockIdx.x] = sh[255];
}

__global__ void scan_partials(int* partial, int nb) {
    __shared__ int sh[512];
    __shared__ int carry;
    int t = threadIdx.x;
    if (t == 0) carry = 0;
    __syncthreads();
    for (int base = 0; base < nb; base += 512) {
        int idx = base + t;
        sh[t] = (idx < nb) ? partial[idx] : 0;
        __syncthreads();
        for (int off = 1; off < 512; off <<= 1) {
            int add = (t >= off) ? sh[t - off] : 0;
            __syncthreads();
            sh[t] += add;
            __syncthreads();
        }
        int excl = carry + ((t == 0) ? 0 : sh[t - 1]);
        if (idx < nb) partial[idx] = excl;
        __syncthreads();
        if (t == 0) carry += sh[511];
        __syncthreads();
    }
}

__global__ void finalize_scan(const int* __restrict__ incl, const int* __restrict__ v,
                              const int* __restrict__ partial,
                              int* __restrict__ excl, int m) {
    int i = blockIdx.x * blockDim.x + threadIdx.x;
    if (i < m) excl[i] = partial[i >> 8] + incl[i] - v[i];
}

// ---------------------------------------------------------------------------
// Phase 1b: re-read chunk, LDS-cursor placement into precomputed per-
// (chunk,bucket) contiguous ranges. rec = (src << 8) | (dst & 255).
// ---------------------------------------------------------------------------
__global__ void scatter_chunks(const void* __restrict__ edges, const int* __restrict__ flag,
                               const int* __restrict__ chunk_base,
                               unsigned int* __restrict__ ebuf,
                               int ne, int nch, int nbkt) {
    __shared__ int cur[1024];
    int c = blockIdx.x, t = threadIdx.x;              // blockDim = 512
    for (int i = t; i < nbkt; i += 512) cur[i] = chunk_base[i * nch + c];
    __syncthreads();
    int beg = c * CHUNK, end = min(ne, beg + CHUNK);
    bool is32 = (*flag != 0);
    for (int i = beg + t; i < end; i += 512) {
        int s, d;
        if (is32) {
            s = ((const int*)edges)[i];
            d = ((const int*)edges)[ne + i];
        } else {
            s = (int)((const long long*)edges)[i];
            d = (int)((const long long*)edges)[ne + i];
        }
        int pos = atomicAdd(&cur[d >> 8], 1);
        ebuf[pos] = ((unsigned int)s << 8) | (unsigned int)(d & (SB - 1));
    }
}

// ---------------------------------------------------------------------------
// Phase 2: one block per bucket. LDS degree histogram + LDS scan ->
// row_ptr, dinv, CU-local scatter of csr_src. (R9: degree-sort perm removed
// — it scattered coalesced writes/self-reads and regressed.)
// ---------------------------------------------------------------------------
__global__ void bucket_finalize(const unsigned int* __restrict__ ebuf,
                                const int* __restrict__ chunk_base,
                                int* __restrict__ row_ptr, float* __restrict__ dinv,
                                int* __restrict__ csr_src,
                                int n, int e, int nch, int nbkt) {
    __shared__ int deg[SB];
    __shared__ int incl[SB];
    __shared__ int cur[SB];
    int b = blockIdx.x, t = threadIdx.x;              // blockDim = SB = 256
    int node0 = b * SB;
    int nn = min(SB, n - node0);
    int base = chunk_base[b * nch];
    int bend = (b == nbkt - 1) ? e : chunk_base[(b + 1) * nch];

    deg[t] = 0;
    __syncthreads();
    for (int i = base + t; i < bend; i += SB)
        atomicAdd(&deg[ebuf[i] & (SB - 1)], 1);
    __syncthreads();

    incl[t] = deg[t];
    __syncthreads();
    for (int off = 1; off < SB; off <<= 1) {
        int add = (t >= off) ? incl[t - off] : 0;
        __syncthreads();
        incl[t] += add;
        __syncthreads();
    }
    int lrow = base + incl[t] - deg[t];
    cur[t] = lrow;
    if (t < nn) {
        row_ptr[node0 + t] = lrow;
        dinv[node0 + t]    = rsqrtf((float)(deg[t] + 1));
    }
    if (b == nbkt - 1 && t == 0) row_ptr[n] = e;
    __syncthreads();

    for (int i = base + t; i < bend; i += SB) {
        unsigned int r = ebuf[i];
        int pos = atomicAdd(&cur[r & (SB - 1)], 1);
        csr_src[pos] = (int)(r >> 8);
    }
}

// ---------------------------------------------------------------------------
// Pack BOTH weights into MFMA B-fragment order in global memory:
//   frag index for element (k, n): [((k>>3) * NC + n) * 8 + (k & 7)]
// (k>>3 == kt*4+q for k = kt*32 + q*8 + j). B-frags then load as direct
// 16-B global reads in the GEMM (no W LDS staging).
// ---------------------------------------------------------------------------
__global__ void w_pack(const float* __restrict__ W1, unsigned short* __restrict__ Wf1,
                       const float* __restrict__ W2, unsigned short* __restrict__ Wf2) {
    int i = blockIdx.x * blockDim.x + threadIdx.x;
    if (i < 128 * 128) {                               // W1: [128][128]
        int k = i >> 7, n = i & 127;
        Wf1[(((k >> 3) * 128) + n) * 8 + (k & 7)] = f2bf(W1[i]);
    }
    if (i < 128 * 64) {                                // W2: [128][64]
        int k = i >> 6, n = i & 63;
        Wf2[(((k >> 3) * 64) + n) * 8 + (k & 7)] = f2bf(W2[i]);
    }
}

// ---------------------------------------------------------------------------
// MFMA GEMM: hs[r][c] = bf16( dinv[r] * sum_k X[r][k] * W[k][c] )
// 128-row M-tile, 256 threads (4 waves x 2 m-tiles). X staged to LDS in
// frag-major order [(kt*4+q)][row][j] (32 KB, conflict-free 16-B reads);
// W read as pre-packed B-frags directly from global (L1-hot, no Wl/barrier).
// Layouts verified: A[m=lane&15][k=q*8+j], B[k=q*8+j][n=lane&15],
// D[row=q*4+i][col=lane&15] (learn_hip m89/m91/m120).
// ---------------------------------------------------------------------------
template <int NC, bool F32IN>
__launch_bounds__(256)
__global__ void gemm_mfma(const void* __restrict__ Xin,
                          const unsigned short* __restrict__ Wf,
                          const float* __restrict__ dinv,
                          unsigned short* __restrict__ hs, int nrows) {
    constexpr int K = 128;
    __shared__ __align__(16) unsigned short Xl[16 * 128 * 8];   // 32 KB

    const int tid  = threadIdx.x;
    const int row0 = blockIdx.x * 128;

    for (int i = tid; i < 128 * 32; i += 256) {        // stage X tile
        int r  = i >> 5;
        int c4 = i & 31;
        int gr = row0 + r;
        ushort4 v = make_ushort4(0, 0, 0, 0);
        if (gr < nrows) {
            if (F32IN) {
                float4 f = ((const float4*)((const float*)Xin + (size_t)gr * K))[c4];
                v.x = f2bf(f.x); v.y = f2bf(f.y); v.z = f2bf(f.z); v.w = f2bf(f.w);
            } else {
                v = ((const ushort4*)((const unsigned short*)Xin + (size_t)gr * K))[c4];
            }
        }
        int k   = c4 * 4;
        int grp = k >> 3;                              // kt*4 + q
        int j0  = k & 7;                               // 0 or 4
        *(ushort4*)(Xl + ((size_t)grp * 128 + r) * 8 + j0) = v;
    }
    __syncthreads();

    const int wv   = tid >> 6;
    const int lane = tid & 63;
    const int m    = lane & 15;
    const int q    = lane >> 4;

    bf16x8 af[2][4];
#pragma unroll
    for (int h = 0; h < 2; ++h)
#pragma unroll
        for (int kt = 0; kt < 4; ++kt)
            af[h][kt] = *(const bf16x8*)(Xl + (((kt * 4 + q) * 128) + h * 64 + wv * 16 + m) * 8);

    int   rbase[2];
    float dv[2][4];
#pragma unroll
    for (int h = 0; h < 2; ++h) {
        rbase[h] = row0 + h * 64 + wv * 16 + q * 4;
#pragma unroll
        for (int i = 0; i < 4; ++i)
            dv[h][i] = (rbase[h] + i < nrows) ? dinv[rbase[h] + i] : 0.f;
    }

#pragma unroll
    for (int nt = 0; nt < NC / 16; ++nt) {
        bf16x8 bfr[4];
#pragma unroll
        for (int kt = 0; kt < 4; ++kt)
            bfr[kt] = *(const bf16x8*)(Wf + (((size_t)(kt * 4 + q) * NC) + nt * 16 + m) * 8);
#pragma unroll
        for (int h = 0; h < 2; ++h) {
            f32x4 acc = {0.f, 0.f, 0.f, 0.f};
#pragma unroll
            for (int kt = 0; kt < 4; ++kt)
                acc = __builtin_amdgcn_mfma_f32_16x16x32_bf16(af[h][kt], bfr[kt], acc, 0, 0, 0);
#pragma unroll
            for (int i = 0; i < 4; ++i) {
                int g = rbase[h] + i;
                if (g < nrows)
                    hs[(size_t)g * NC + nt * 16 + m] = f2bf(acc[i] * dv[h][i]);
            }
        }
    }
}

// ---------------------------------------------------------------------------
// CSR gather-reduce + epilogue, bf16 features (fp32 accumulate).
// R8 form (best known): natural node order, TPN = F/8 lanes per node, uint4
// per lane, batches of 8 edges in flight.
// ---------------------------------------------------------------------------
template <int F, bool RELU, bool OUTBF>
__launch_bounds__(256)
__global__ void aggregate_bf16(const int* __restrict__ row_ptr,
                               const int* __restrict__ csr_src,
                               const uint4* __restrict__ hsu,
                               const float* __restrict__ dinv,
                               const float* __restrict__ b,
                               void* __restrict__ out, int n) {
    constexpr int TPN = F / 8;          // lanes per node (16 / 8)
    constexpr int NPB = 256 / TPN;      // nodes per block (16 / 32)
    int node = blockIdx.x * NPB + threadIdx.x / TPN;
    int t    = threadIdx.x % TPN;
    if (node >= n) return;

    uint4 u = hsu[(size_t)node * TPN + t];           // self-loop term
    float a[8];
    a[0] = bflo(u.x); a[1] = bfhi(u.x); a[2] = bflo(u.y); a[3] = bfhi(u.y);
    a[4] = bflo(u.z); a[5] = bfhi(u.z); a[6] = bflo(u.w); a[7] = bfhi(u.w);

    int beg = row_ptr[node], end = row_ptr[node + 1];
    for (int e = beg; e < end; e += 8) {
        int rem = end - e;                            // >= 1
        int s[8];
#pragma unroll
        for (int j = 0; j < 8; ++j)
            s[j] = csr_src[e + (j < rem ? j : 0)];
        uint4 v[8];
#pragma unroll
        for (int j = 0; j < 8; ++j)
            v[j] = hsu[(size_t)s[j] * TPN + t];
#pragma unroll
        for (int j = 0; j < 8; ++j) {
            if (j < rem) {
                a[0] += bflo(v[j].x); a[1] += bfhi(v[j].x);
                a[2] += bflo(v[j].y); a[3] += bfhi(v[j].y);
                a[4] += bflo(v[j].z); a[5] += bfhi(v[j].z);
                a[6] += bflo(v[j].w); a[7] += bfhi(v[j].w);
            }
        }
    }

    float dvn = dinv[node];
    float4 b0 = ((const float4*)b)[2 * t];
    float4 b1 = ((const float4*)b)[2 * t + 1];
    float o[8];
    o[0] = a[0] * dvn + b0.x; o[1] = a[1] * dvn + b0.y;
    o[2] = a[2] * dvn + b0.z; o[3] = a[3] * dvn + b0.w;
    o[4] = a[4] * dvn + b1.x; o[5] = a[5] * dvn + b1.y;
    o[6] = a[6] * dvn + b1.z; o[7] = a[7] * dvn + b1.w;
    if (RELU) {
#pragma unroll
        for (int j = 0; j < 8; ++j) o[j] = fmaxf(o[j], 0.f);
    }
    if (OUTBF) {
        uint4 ov;
        ov.x = (unsigned int)f2bf(o[0]) | ((unsigned int)f2bf(o[1]) << 16);
        ov.y = (unsigned int)f2bf(o[2]) | ((unsigned int)f2bf(o[3]) << 16);
        ov.z = (unsigned int)f2bf(o[4]) | ((unsigned int)f2bf(o[5]) << 16);
        ov.w = (unsigned int)f2bf(o[6]) | ((unsigned int)f2bf(o[7]) << 16);
        ((uint4*)out)[(size_t)node * TPN + t] = ov;
    } else {
        float4* op = (float4*)out + (size_t)node * (F / 4) + 2 * t;
        op[0] = make_float4(o[0], o[1], o[2], o[3]);
        op[1] = make_float4(o[4], o[5], o[6], o[7]);
    }
}

// ---------------------------------------------------------------------------
extern "C" void kernel_launch(void* const* d_in, const int* in_sizes, int n_in,
                              void* d_out, int out_size, void* d_ws, size_t ws_size,
                              hipStream_t stream) {
    const void*  edge = d_in[0];
    const float* x    = (const float*)d_in[1];
    const float* W1   = (const float*)d_in[2];
    const float* b1   = (const float*)d_in[3];
    const float* W2   = (const float*)d_in[4];
    const float* b2   = (const float*)d_in[5];
    float* out = (float*)d_out;

    const int E    = in_sizes[0] / 2;
    const int N    = in_sizes[1] / NFEATS;
    const int NBKT = (N + SB - 1) / SB;        // 391
    const int NCH  = (E + CHUNK - 1) / CHUNK;  // 391
    const int M    = NBKT * NCH;               // histogram matrix size

    char* w = (char*)d_ws;
    auto carve = [&](size_t bytes) { void* p = w; w += (bytes + 255) & ~(size_t)255; return p; };
    int*            flag       = (int*)           carve(256);
    int*            histT      = (int*)           carve(sizeof(int) * (size_t)M);
    int*            incl       = (int*)           carve(sizeof(int) * (size_t)M);
    int*            partial    = (int*)           carve(sizeof(int) * 4096);
    int*            chunk_base = (int*)           carve(sizeof(int) * (size_t)M);
    int*            row_ptr    = (int*)           carve(sizeof(int) * ((size_t)N + 1));
    float*          dinv       = (float*)         carve(sizeof(float) * (size_t)N);
    unsigned int*   ebuf       = (unsigned int*)  carve(sizeof(int) * (size_t)E);
    int*            csr_src    = (int*)           carve(sizeof(int) * (size_t)E);
    unsigned short* Wf1        = (unsigned short*)carve(2 * (size_t)NFEATS * NHIDS);
    unsigned short* Wf2        = (unsigned short*)carve(2 * (size_t)NHIDS * NOUT);
    unsigned short* hs1        = (unsigned short*)carve(2 * (size_t)N * NHIDS);
    unsigned short* h1         = (unsigned short*)carve(2 * (size_t)N * NHIDS);
    unsigned short* hs2        = (unsigned short*)carve(2 * (size_t)N * NOUT);

    const int B   = 256;
    const int nbS = (M + 255) / 256;           // scan blocks over histogram

    detect_kernel<<<1, 64, 0, stream>>>(edge, flag, (long long)N);

    // CSR build: chunk histograms -> scan -> LDS-cursor partition -> finalize
    hist_kernel<<<NCH, 512, 0, stream>>>(edge, flag, histT, E, NCH, NBKT);
    scan_block<<<nbS, 256, 0, stream>>>(histT, incl, partial, M);
    scan_partials<<<1, 512, 0, stream>>>(partial, nbS);
    finalize_scan<<<nbS, 256, 0, stream>>>(incl, histT, partial, chunk_base, M);
    scatter_chunks<<<NCH, 512, 0, stream>>>(edge, flag, chunk_base, ebuf, E, NCH, NBKT);
    bucket_finalize<<<NBKT, SB, 0, stream>>>(ebuf, chunk_base, row_ptr, dinv, csr_src,
                                             N, E, NCH, NBKT);

    // pack both weights into B-frag order (one launch)
    w_pack<<<(128 * 128 + B - 1) / B, B, 0, stream>>>(W1, Wf1, W2, Wf2);

    // ---- layer 1 ----
    gemm_mfma<NHIDS, true><<<(N + 127) / 128, B, 0, stream>>>(x, Wf1, dinv, hs1, N);
    {
        constexpr int NPB = 256 / (NHIDS / 8);   // 16 nodes per block
        aggregate_bf16<NHIDS, true, true><<<(N + NPB - 1) / NPB, B, 0, stream>>>(
            row_ptr, csr_src, (const uint4*)hs1, dinv, b1, h1, N);
    }

    // ---- layer 2 ----
    gemm_mfma<NOUT, false><<<(N + 127) / 128, B, 0, stream>>>(h1, Wf2, dinv, hs2, N);
    {
        constexpr int NPB = 256 / (NOUT / 8);    // 32 nodes per block
        aggregate_bf16<NOUT, false, false><<<(N + NPB - 1) / NPB, B, 0, stream>>>(
            row_ptr, csr_src, (const uint4*)hs2, dinv, b2, out, N);
    }
}